// Round 5
// baseline (2047.461 us; speedup 1.0000x reference)
//
#include <hip/hip_runtime.h>

#define T_ENC 20
#define T_DEC 30
#define WAVES 8           // 8 waves/block = 2 per SIMD, 32 batch elements/wave
#define EPB (WAVES * 32)  // 256 elements per block

typedef __attribute__((ext_vector_type(8))) short short8;    // 8 bf16 = 4 VGPR
typedef __attribute__((ext_vector_type(16))) float f32x16;   // MFMA 32x32 acc

#if __has_builtin(__builtin_amdgcn_exp2f)
#define EXP2F(x) __builtin_amdgcn_exp2f(x)
#else
#define EXP2F(x) exp2f(x)
#endif
#if __has_builtin(__builtin_amdgcn_rcpf)
#define RCPF(x) __builtin_amdgcn_rcpf(x)
#else
#define RCPF(x) (1.0f / (x))
#endif

#define LOG2E 1.4426950408889634f
#define TWO_LOG2E 2.8853900817779268f

#define MFMA32(a, b, c) __builtin_amdgcn_mfma_f32_32x32x16_bf16(a, b, c, 0, 0, 0)

__global__ __launch_bounds__(512)
__attribute__((amdgpu_waves_per_eu(2, 2)))   // 2 waves/SIMD => 256-VGPR budget
void SinglePrediction_88493506167138_kernel(
    const float* __restrict__ x,         // [B][20][2]
    const float* __restrict__ W_ih_enc,  // [256][2]
    const float* __restrict__ W_hh_enc,  // [256][64]
    const float* __restrict__ b_ih_enc,  // [256]
    const float* __restrict__ b_hh_enc,  // [256]
    const float* __restrict__ W_ih_dec,  // [256][64]
    const float* __restrict__ W_hh_dec,  // [256][64]
    const float* __restrict__ b_ih_dec,  // [256]
    const float* __restrict__ b_hh_dec,  // [256]
    const float* __restrict__ W_emb,     // [2][64]
    const float* __restrict__ b_emb,     // [2]
    float* __restrict__ out,             // [B][30][2]
    float* __restrict__ ws,              // [30][B][2] staging (if use_ws)
    int Btot, int use_ws)
{
  // LDS: 2*36864 (W hi/lo, 288 rows) + 65536 (hT) + 1024 = 140,288 B
  __shared__ __align__(16) unsigned short Wh[288 * 64];
  __shared__ __align__(16) unsigned short Wl[288 * 64];
  __shared__ __align__(16) unsigned short hT[WAVES][2][32 * 64];
  __shared__ float bsum_l[256];

  const int tid = threadIdx.x;
  const int lane = tid & 63;
  const int wid = tid >> 6;
  const int hi5 = lane >> 5;
  const int l31 = lane & 31;
  const int beb = blockIdx.x * EPB;

  // ---- stage encoder W_hh * gate-scale as bf16 hi/lo (Dekker split),
  //      XOR-swizzled: elem (row,k) -> row*64 + (k ^ ((row&7)<<3))
  for (int i = tid; i < 256 * 64; i += 512) {
    int row = i >> 6, k = i & 63;
    float sc = ((row >> 6) == 2) ? TWO_LOG2E : LOG2E;  // g-gate rows get 2L
    float w = W_hh_enc[i] * sc;
    unsigned u = __float_as_uint(w);
    float lo = w - __uint_as_float(u & 0xffff0000u);
    int si = (row << 6) | (k ^ ((row & 7) << 3));
    Wh[si] = (unsigned short)(u >> 16);
    Wl[si] = (unsigned short)(__float_as_uint(lo) >> 16);
  }
  if (tid < 256) {
    float sc = ((tid >> 6) == 2) ? TWO_LOG2E : LOG2E;
    bsum_l[tid] = (b_ih_enc[tid] + b_hh_enc[tid]) * sc;
  }
  // ---- zero this wave's hT (h0 = 0) ----
  {
    float4 z = {0.f, 0.f, 0.f, 0.f};
    float4* p = (float4*)&hT[wid][0][0];
    for (int i = lane; i < 512; i += 64) p[i] = z;
  }
  __syncthreads();

  // per-lane constants (gate row n = nt*32 + l31), scaled like W
  float biasv[8], wi0[8], wi1[8];
#pragma unroll
  for (int nt = 0; nt < 8; nt++) {
    int n = nt * 32 + l31;
    float sc = ((n >> 6) == 2) ? TWO_LOG2E : LOG2E;
    biasv[nt] = bsum_l[n];
    float2 wv = *(const float2*)&W_ih_enc[2 * n];
    wi0[nt] = wv.x * sc;
    wi1[nt] = wv.y * sc;
  }

  float c01[2][16];
#pragma unroll
  for (int p = 0; p < 2; p++)
#pragma unroll
    for (int q = 0; q < 16; q++) c01[p][q] = 0.f;

  const int sw = (l31 & 7) << 3;  // swizzle term (same for A and B)
  const int kbase = hi5 << 3;     // k-offset of this lane half

  short8 ah[4], al[4];
  auto loadA = [&]() {
#pragma unroll
    for (int kt = 0; kt < 4; kt++) {
      int sk = (kt * 16 + kbase) ^ sw;
      ah[kt] = *(const short8*)&hT[wid][0][(l31 << 6) + sk];
      al[kt] = *(const short8*)&hT[wid][1][(l31 << 6) + sk];
    }
  };

  // 4 N-tiles (rbase..rbase+3), hi*hi + lo*hi + hi*lo
  auto gemm4 = [&](f32x16 (&A)[4], int rbase) {
#pragma unroll
    for (int kt = 0; kt < 4; kt++) {
      const int sk = (kt * 16 + kbase) ^ sw;
      short8 bh[4], bl[4];
#pragma unroll
      for (int j = 0; j < 4; j++) {
        const int r = (rbase + j) * 32 + l31;
        bh[j] = *(const short8*)&Wh[(r << 6) + sk];
        bl[j] = *(const short8*)&Wl[(r << 6) + sk];
      }
#pragma unroll
      for (int j = 0; j < 4; j++) A[j] = MFMA32(ah[kt], bh[j], A[j]);
#pragma unroll
      for (int j = 0; j < 4; j++) A[j] = MFMA32(al[kt], bh[j], A[j]);
#pragma unroll
      for (int j = 0; j < 4; j++) A[j] = MFMA32(ah[kt], bl[j], A[j]);
    }
  };

  // phase-2 epilogue: g,o gates -> c,h update + hT write (gates exp2-scaled)
  auto finish_step = [&](f32x16 (&A)[4], float (&ig)[2][16]) {
#pragma unroll
    for (int p = 0; p < 2; p++)
#pragma unroll
      for (int q = 0; q < 16; q++) {
        float eg = EXP2F(A[p][q]);                 // g pre-scaled by 2*log2e
        float gg = 1.f - 2.f * RCPF(eg + 1.f);
        float og = RCPF(1.f + EXP2F(-A[2 + p][q]));
        float cn = fmaf(ig[p][q], gg, c01[p][q]);  // c01 holds fg*c_old
        c01[p][q] = cn;
        float ec = EXP2F(TWO_LOG2E * cn);
        float th = 1.f - 2.f * RCPF(ec + 1.f);
        float hn = og * th;
        unsigned u = __float_as_uint(hn);
        float lo = hn - __uint_as_float(u & 0xffff0000u);
        const int row = (q & 3) + 8 * (q >> 2) + 4 * hi5;
        const int col = l31 + 32 * p;
        const int si = (row << 6) | (col ^ ((row & 7) << 3));
        hT[wid][0][si] = (unsigned short)(u >> 16);
        hT[wid][1][si] = (unsigned short)(__float_as_uint(lo) >> 16);
      }
  };

  // ================= encoder =================
#pragma unroll 1
  for (int t = 0; t < T_ENC; t++) {
    loadA();
    f32x16 A[4];
    float ig[2][16];
    // ---- phase 1: tiles 0..3 (i, f) ----
#pragma unroll
    for (int q = 0; q < 16; q++) {
      const int row = (q & 3) + 8 * (q >> 2) + 4 * hi5;
      const float2 xq =
          *(const float2*)&x[((size_t)(beb + wid * 32 + row)) * 40 + 2 * t];
#pragma unroll
      for (int j = 0; j < 4; j++)
        A[j][q] = fmaf(xq.x, wi0[j], fmaf(xq.y, wi1[j], biasv[j]));
    }
    gemm4(A, 0);
#pragma unroll
    for (int p = 0; p < 2; p++)
#pragma unroll
      for (int q = 0; q < 16; q++) {
        ig[p][q] = RCPF(1.f + EXP2F(-A[p][q]));
        c01[p][q] *= RCPF(1.f + EXP2F(-A[2 + p][q]));  // cpart = fg*c_old
      }
    // ---- phase 2: tiles 4..7 (g, o) ----
#pragma unroll
    for (int q = 0; q < 16; q++) {
      const int row = (q & 3) + 8 * (q >> 2) + 4 * hi5;
      const float2 xq =
          *(const float2*)&x[((size_t)(beb + wid * 32 + row)) * 40 + 2 * t];
#pragma unroll
      for (int j = 0; j < 4; j++)
        A[j][q] = fmaf(xq.x, wi0[4 + j], fmaf(xq.y, wi1[4 + j], biasv[4 + j]));
    }
    gemm4(A, 4);
    finish_step(A, ig);
  }

  // ================= swap to decoder weights (+ W_emb rows 256..287) =======
  __syncthreads();
  for (int i = tid; i < 288 * 64; i += 512) {
    int row = i >> 6, k = i & 63;
    float w;
    if (row < 256) {
      float sc = ((row >> 6) == 2) ? TWO_LOG2E : LOG2E;
      w = (W_ih_dec[i] + W_hh_dec[i]) * sc;  // dec input == h: fold ih+hh
    } else if (row < 258) {
      w = W_emb[(row - 256) * 64 + k];       // unscaled
    } else {
      w = 0.f;
    }
    unsigned u = __float_as_uint(w);
    float lo = w - __uint_as_float(u & 0xffff0000u);
    int si = (row << 6) | (k ^ ((row & 7) << 3));
    Wh[si] = (unsigned short)(u >> 16);
    Wl[si] = (unsigned short)(__float_as_uint(lo) >> 16);
  }
  if (tid < 256) {
    float sc = ((tid >> 6) == 2) ? TWO_LOG2E : LOG2E;
    bsum_l[tid] = (b_ih_dec[tid] + b_hh_dec[tid]) * sc;
  }
  __syncthreads();

#pragma unroll
  for (int nt = 0; nt < 8; nt++) biasv[nt] = bsum_l[nt * 32 + l31];
  const float bev = (l31 == 0) ? b_emb[0] : b_emb[1];

  // pos_{tout} from current A-frags (h after step tout+1): 9th N-tile MFMA
  auto do_pos = [&](int tout) {
    f32x16 accP;
#pragma unroll
    for (int q = 0; q < 16; q++) accP[q] = 0.f;
#pragma unroll
    for (int kt = 0; kt < 4; kt++) {
      int sk = (kt * 16 + kbase) ^ sw;
      int r = 256 + l31;
      short8 beh = *(const short8*)&Wh[(r << 6) + sk];
      short8 bel = *(const short8*)&Wl[(r << 6) + sk];
      accP = MFMA32(ah[kt], beh, accP);
      accP = MFMA32(al[kt], beh, accP);
      accP = MFMA32(ah[kt], bel, accP);
    }
    if (l31 < 2) {
#pragma unroll
      for (int q = 0; q < 16; q++) {
        int row = (q & 3) + 8 * (q >> 2) + 4 * hi5;
        size_t e = (size_t)(beb + wid * 32 + row);
        float v = accP[q] + bev;
        if (use_ws) {
          // [T][B][2]: per wave-step the 32 stores cover one contiguous
          // 256 B region -> full-line write-combine, no RMW fetch
          ws[((size_t)tout * Btot + e) * 2 + l31] = v;
        } else {
          out[e * 60 + 2 * tout + l31] = v;
        }
      }
    }
  };

  // ================= decoder =================
#pragma unroll 1
  for (int t = 0; t < T_DEC; t++) {
    loadA();
    if (t > 0) do_pos(t - 1);
    f32x16 A[4];
    float ig[2][16];
    // ---- phase 1: tiles 0..3 (i, f) ----
#pragma unroll
    for (int j = 0; j < 4; j++)
#pragma unroll
      for (int q = 0; q < 16; q++) A[j][q] = biasv[j];
    gemm4(A, 0);
#pragma unroll
    for (int p = 0; p < 2; p++)
#pragma unroll
      for (int q = 0; q < 16; q++) {
        ig[p][q] = RCPF(1.f + EXP2F(-A[p][q]));
        c01[p][q] *= RCPF(1.f + EXP2F(-A[2 + p][q]));
      }
    // ---- phase 2: tiles 4..7 (g, o) ----
#pragma unroll
    for (int j = 0; j < 4; j++)
#pragma unroll
      for (int q = 0; q < 16; q++) A[j][q] = biasv[4 + j];
    gemm4(A, 4);
    finish_step(A, ig);
  }
  loadA();
  do_pos(T_DEC - 1);
}

// ws [30][B][2] -> out [B][30][2]; reads coalesced (consecutive e), writes
// cover contiguous 240 B per thread (wave covers 15 KB fully -> WC in L2)
__global__ __launch_bounds__(256)
void pos_transpose_kernel(const float* __restrict__ ws,
                          float* __restrict__ out, int Btot) {
  const int e = blockIdx.x * 256 + threadIdx.x;
  float2 v[T_DEC];
#pragma unroll
  for (int t = 0; t < T_DEC; t++)
    v[t] = ((const float2*)ws)[(size_t)t * Btot + e];
  float2* o = (float2*)(out + (size_t)e * 60);
#pragma unroll
  for (int t = 0; t < T_DEC; t++) o[t] = v[t];
}

extern "C" void kernel_launch(void* const* d_in, const int* in_sizes, int n_in,
                              void* d_out, int out_size, void* d_ws, size_t ws_size,
                              hipStream_t stream) {
  const float* x        = (const float*)d_in[0];
  const float* W_ih_enc = (const float*)d_in[1];
  const float* W_hh_enc = (const float*)d_in[2];
  const float* b_ih_enc = (const float*)d_in[3];
  const float* b_hh_enc = (const float*)d_in[4];
  const float* W_ih_dec = (const float*)d_in[5];
  const float* W_hh_dec = (const float*)d_in[6];
  const float* b_ih_dec = (const float*)d_in[7];
  const float* b_hh_dec = (const float*)d_in[8];
  const float* W_emb    = (const float*)d_in[9];
  const float* b_emb    = (const float*)d_in[10];
  float* out = (float*)d_out;

  const int B = in_sizes[0] / (T_ENC * 2);  // 65536
  const int grid = B / EPB;                 // 256 = 1 block per CU
  const size_t ws_needed = (size_t)B * T_DEC * 2 * sizeof(float);
  const int use_ws = (ws_size >= ws_needed) ? 1 : 0;

  hipLaunchKernelGGL(SinglePrediction_88493506167138_kernel,
                     dim3(grid), dim3(512), 0, stream,
                     x, W_ih_enc, W_hh_enc, b_ih_enc, b_hh_enc,
                     W_ih_dec, W_hh_dec, b_ih_dec, b_hh_dec,
                     W_emb, b_emb, out, (float*)d_ws, B, use_ws);
  if (use_ws) {
    hipLaunchKernelGGL(pos_transpose_kernel, dim3(B / 256), dim3(256), 0,
                       stream, (const float*)d_ws, out, B);
  }
}

// Round 6
// 1353.824 us; speedup vs baseline: 1.5124x; 1.5124x over previous
//
#include <hip/hip_runtime.h>

#define T_ENC 20
#define T_DEC 30
#define WAVES 4           // 4 waves/block (256 thr) — the shape that gets 256 VGPRs
#define EPB (WAVES * 32)  // 128 elements per block

typedef __attribute__((ext_vector_type(8))) _Float16 half8;  // 8 f16 = 4 VGPR
typedef __attribute__((ext_vector_type(16))) float f32x16;   // MFMA 32x32 acc

#if __has_builtin(__builtin_amdgcn_exp2f)
#define EXP2F(x) __builtin_amdgcn_exp2f(x)
#else
#define EXP2F(x) exp2f(x)
#endif
#if __has_builtin(__builtin_amdgcn_rcpf)
#define RCPF(x) __builtin_amdgcn_rcpf(x)
#else
#define RCPF(x) (1.0f / (x))
#endif

#define LOG2E 1.4426950408889634f
#define TWO_LOG2E 2.8853900817779268f

#define MFMA16(a, b, c) __builtin_amdgcn_mfma_f32_32x32x16_f16(a, b, c, 0, 0, 0)

__device__ __forceinline__ unsigned short h2u(_Float16 h) {
  union { _Float16 h; unsigned short u; } v;
  v.h = h;
  return v.u;
}

__global__ __launch_bounds__(256, 2)   // 4 waves, min 2 waves/EU -> <=256 VGPR
void SinglePrediction_88493506167138_kernel(
    const float* __restrict__ x,         // [B][20][2]
    const float* __restrict__ W_ih_enc,  // [256][2]
    const float* __restrict__ W_hh_enc,  // [256][64]
    const float* __restrict__ b_ih_enc,  // [256]
    const float* __restrict__ b_hh_enc,  // [256]
    const float* __restrict__ W_ih_dec,  // [256][64]
    const float* __restrict__ W_hh_dec,  // [256][64]
    const float* __restrict__ b_ih_dec,  // [256]
    const float* __restrict__ b_hh_dec,  // [256]
    const float* __restrict__ W_emb,     // [2][64]
    const float* __restrict__ b_emb,     // [2]
    float* __restrict__ out,             // [B][30][2]
    float* __restrict__ ws,              // [30][B][2] staging (if use_ws)
    int Btot, int use_ws)
{
  // LDS: 36864 (W fp16, 288 rows) + 2*16384 (hT hi/lo) + 1024 = 70,656 B
  // -> 2 blocks/CU (141 KB < 160 KB), 8 waves/CU = 2 waves/SIMD
  __shared__ __align__(16) unsigned short Wf[288 * 64];
  __shared__ __align__(16) unsigned short hTh[WAVES][32 * 64];
  __shared__ __align__(16) unsigned short hTl[WAVES][32 * 64];
  __shared__ float bsum_l[256];

  const int tid = threadIdx.x;
  const int lane = tid & 63;
  const int wid = tid >> 6;
  const int hi5 = lane >> 5;
  const int l31 = lane & 31;
  const int beb = blockIdx.x * EPB;

  // ---- stage encoder W_hh * gate-scale as fp16, XOR-swizzled:
  //      elem (row,k) -> row*64 + (k ^ ((row&7)<<3))
  for (int i = tid; i < 256 * 64; i += 256) {
    int row = i >> 6, k = i & 63;
    float sc = ((row >> 6) == 2) ? TWO_LOG2E : LOG2E;  // g-gate rows get 2L
    _Float16 wv = (_Float16)(W_hh_enc[i] * sc);
    Wf[(row << 6) | (k ^ ((row & 7) << 3))] = h2u(wv);
  }
  if (tid < 256) {
    float sc = ((tid >> 6) == 2) ? TWO_LOG2E : LOG2E;
    bsum_l[tid] = (b_ih_enc[tid] + b_hh_enc[tid]) * sc;
  }
  // ---- zero this wave's hT (h0 = 0) ----
  {
    float4 z = {0.f, 0.f, 0.f, 0.f};
    float4* p0 = (float4*)&hTh[wid][0];
    float4* p1 = (float4*)&hTl[wid][0];
    for (int i = lane; i < 256; i += 64) { p0[i] = z; p1[i] = z; }
  }
  __syncthreads();

  // per-lane constants (gate row n = nt*32 + l31), scaled like W
  float biasv[8], wi0[8], wi1[8];
#pragma unroll
  for (int nt = 0; nt < 8; nt++) {
    int n = nt * 32 + l31;
    float sc = ((n >> 6) == 2) ? TWO_LOG2E : LOG2E;
    biasv[nt] = bsum_l[n];
    float2 wv = *(const float2*)&W_ih_enc[2 * n];
    wi0[nt] = wv.x * sc;
    wi1[nt] = wv.y * sc;
  }

  float c01[2][16];
#pragma unroll
  for (int p = 0; p < 2; p++)
#pragma unroll
    for (int q = 0; q < 16; q++) c01[p][q] = 0.f;

  const int sw = (l31 & 7) << 3;  // swizzle term (same for A and B)
  const int kbase = hi5 << 3;     // k-offset of this lane half

  half8 ah[4], al[4];
  auto loadA = [&]() {
#pragma unroll
    for (int kt = 0; kt < 4; kt++) {
      int sk = (kt * 16 + kbase) ^ sw;
      ah[kt] = *(const half8*)&hTh[wid][(l31 << 6) + sk];
      al[kt] = *(const half8*)&hTl[wid][(l31 << 6) + sk];
    }
  };

  // gates MFMA: 8 N-tiles x 4 K-chunks x (h_hi + h_lo) products
  auto gemm_main = [&](f32x16 (&acc)[8]) {
#pragma unroll
    for (int kt = 0; kt < 4; kt++) {
      const int sk = (kt * 16 + kbase) ^ sw;
      half8 b[8];
#pragma unroll
      for (int nt = 0; nt < 8; nt++)
        b[nt] = *(const half8*)&Wf[((nt * 32 + l31) << 6) + sk];
#pragma unroll
      for (int nt = 0; nt < 8; nt++) acc[nt] = MFMA16(ah[kt], b[nt], acc[nt]);
#pragma unroll
      for (int nt = 0; nt < 8; nt++) acc[nt] = MFMA16(al[kt], b[nt], acc[nt]);
    }
  };

  // gates pre-scaled by log2e (2*log2e for g) -> exp2 direct
  auto finish_step = [&](f32x16 (&acc)[8]) {
#pragma unroll
    for (int p = 0; p < 2; p++)
#pragma unroll
      for (int q = 0; q < 16; q++) {
        float ig = RCPF(1.f + EXP2F(-acc[0 + p][q]));
        float fg = RCPF(1.f + EXP2F(-acc[2 + p][q]));
        float eg = EXP2F(acc[4 + p][q]);
        float gg = 1.f - 2.f * RCPF(eg + 1.f);
        float og = RCPF(1.f + EXP2F(-acc[6 + p][q]));
        float cn = fmaf(fg, c01[p][q], ig * gg);
        c01[p][q] = cn;
        float ec = EXP2F(TWO_LOG2E * cn);
        float th = 1.f - 2.f * RCPF(ec + 1.f);
        float hn = og * th;
        _Float16 hh = (_Float16)hn;
        _Float16 hl = (_Float16)(hn - (float)hh);
        const int row = (q & 3) + 8 * (q >> 2) + 4 * hi5;
        const int col = l31 + 32 * p;
        const int si = (row << 6) | (col ^ ((row & 7) << 3));
        hTh[wid][si] = h2u(hh);
        hTl[wid][si] = h2u(hl);
      }
  };

  // ================= encoder =================
#pragma unroll 1
  for (int t = 0; t < T_ENC; t++) {
    loadA();
    f32x16 acc[8];
#pragma unroll
    for (int q = 0; q < 16; q++) {
      const int row = (q & 3) + 8 * (q >> 2) + 4 * hi5;
      const float2 xq =
          *(const float2*)&x[((size_t)(beb + wid * 32 + row)) * 40 + 2 * t];
#pragma unroll
      for (int nt = 0; nt < 8; nt++)
        acc[nt][q] = fmaf(xq.x, wi0[nt], fmaf(xq.y, wi1[nt], biasv[nt]));
    }
    gemm_main(acc);
    finish_step(acc);
  }

  // ================= swap to decoder weights (+ W_emb rows 256..287) =======
  __syncthreads();
  for (int i = tid; i < 288 * 64; i += 256) {
    int row = i >> 6, k = i & 63;
    float w;
    if (row < 256) {
      float sc = ((row >> 6) == 2) ? TWO_LOG2E : LOG2E;
      w = (W_ih_dec[i] + W_hh_dec[i]) * sc;  // dec input == h: fold ih+hh
    } else if (row < 258) {
      w = W_emb[(row - 256) * 64 + k];       // unscaled
    } else {
      w = 0.f;
    }
    _Float16 wv = (_Float16)w;
    Wf[(row << 6) | (k ^ ((row & 7) << 3))] = h2u(wv);
  }
  if (tid < 256) {
    float sc = ((tid >> 6) == 2) ? TWO_LOG2E : LOG2E;
    bsum_l[tid] = (b_ih_dec[tid] + b_hh_dec[tid]) * sc;
  }
  __syncthreads();

#pragma unroll
  for (int nt = 0; nt < 8; nt++) biasv[nt] = bsum_l[nt * 32 + l31];
  const float bev = (l31 == 0) ? b_emb[0] : b_emb[1];

  // pos_{tout} from current A-frags (h after step tout+1): 9th N-tile MFMA
  auto do_pos = [&](int tout) {
    f32x16 accP;
#pragma unroll
    for (int q = 0; q < 16; q++) accP[q] = 0.f;
#pragma unroll
    for (int kt = 0; kt < 4; kt++) {
      int sk = (kt * 16 + kbase) ^ sw;
      int r = 256 + l31;
      half8 be = *(const half8*)&Wf[(r << 6) + sk];
      accP = MFMA16(ah[kt], be, accP);
      accP = MFMA16(al[kt], be, accP);
    }
    if (l31 < 2) {
#pragma unroll
      for (int q = 0; q < 16; q++) {
        int row = (q & 3) + 8 * (q >> 2) + 4 * hi5;
        size_t e = (size_t)(beb + wid * 32 + row);
        float v = accP[q] + bev;
        if (use_ws) {
          // [T][B][2]: per wave-step the stores cover one contiguous 256 B
          // region -> full-line write-combine, no RMW fetch
          ws[((size_t)tout * Btot + e) * 2 + l31] = v;
        } else {
          out[e * 60 + 2 * tout + l31] = v;
        }
      }
    }
  };

  // ================= decoder =================
#pragma unroll 1
  for (int t = 0; t < T_DEC; t++) {
    loadA();
    if (t > 0) do_pos(t - 1);
    f32x16 acc[8];
#pragma unroll
    for (int nt = 0; nt < 8; nt++)
#pragma unroll
      for (int q = 0; q < 16; q++) acc[nt][q] = biasv[nt];
    gemm_main(acc);
    finish_step(acc);
  }
  loadA();
  do_pos(T_DEC - 1);
}

// ws [30][B][2] -> out [B][30][2]; reads coalesced, per-thread writes cover
// a contiguous 240 B span (wave covers 15 KB fully -> write-combine in L2)
__global__ __launch_bounds__(256)
void pos_transpose_kernel(const float* __restrict__ ws,
                          float* __restrict__ out, int Btot) {
  const int e = blockIdx.x * 256 + threadIdx.x;
  float2 v[T_DEC];
#pragma unroll
  for (int t = 0; t < T_DEC; t++)
    v[t] = ((const float2*)ws)[(size_t)t * Btot + e];
  float2* o = (float2*)(out + (size_t)e * 60);
#pragma unroll
  for (int t = 0; t < T_DEC; t++) o[t] = v[t];
}

extern "C" void kernel_launch(void* const* d_in, const int* in_sizes, int n_in,
                              void* d_out, int out_size, void* d_ws, size_t ws_size,
                              hipStream_t stream) {
  const float* x        = (const float*)d_in[0];
  const float* W_ih_enc = (const float*)d_in[1];
  const float* W_hh_enc = (const float*)d_in[2];
  const float* b_ih_enc = (const float*)d_in[3];
  const float* b_hh_enc = (const float*)d_in[4];
  const float* W_ih_dec = (const float*)d_in[5];
  const float* W_hh_dec = (const float*)d_in[6];
  const float* b_ih_dec = (const float*)d_in[7];
  const float* b_hh_dec = (const float*)d_in[8];
  const float* W_emb    = (const float*)d_in[9];
  const float* b_emb    = (const float*)d_in[10];
  float* out = (float*)d_out;

  const int B = in_sizes[0] / (T_ENC * 2);  // 65536
  const int grid = B / EPB;                 // 512 = 2 resident blocks per CU
  const size_t ws_needed = (size_t)B * T_DEC * 2 * sizeof(float);
  const int use_ws = (ws_size >= ws_needed) ? 1 : 0;

  hipLaunchKernelGGL(SinglePrediction_88493506167138_kernel,
                     dim3(grid), dim3(256), 0, stream,
                     x, W_ih_enc, W_hh_enc, b_ih_enc, b_hh_enc,
                     W_ih_dec, W_hh_dec, b_ih_dec, b_hh_dec,
                     W_emb, b_emb, out, (float*)d_ws, B, use_ws);
  if (use_ws) {
    hipLaunchKernelGGL(pos_transpose_kernel, dim3(B / 256), dim3(256), 0,
                       stream, (const float*)d_ws, out, B);
  }
}

// Round 7
// 629.364 us; speedup vs baseline: 3.2532x; 2.1511x over previous
//
#include <hip/hip_runtime.h>

#define T_ENC 20
#define T_DEC 30
#define WAVES 4           // 4 waves/block (256 thr) — the shape that gets 256 VGPRs
#define EPB (WAVES * 32)  // 128 elements per block

typedef __attribute__((ext_vector_type(8))) _Float16 half8;  // 8 f16 = 4 VGPR
typedef __attribute__((ext_vector_type(16))) float f32x16;   // MFMA 32x32 acc

#if __has_builtin(__builtin_amdgcn_exp2f)
#define EXP2F(x) __builtin_amdgcn_exp2f(x)
#else
#define EXP2F(x) exp2f(x)
#endif
#if __has_builtin(__builtin_amdgcn_rcpf)
#define RCPF(x) __builtin_amdgcn_rcpf(x)
#else
#define RCPF(x) (1.0f / (x))
#endif

#define LOG2E 1.4426950408889634f
#define TWO_LOG2E 2.8853900817779268f

#define MFMA16(a, b, c) __builtin_amdgcn_mfma_f32_32x32x16_f16(a, b, c, 0, 0, 0)

__device__ __forceinline__ unsigned short h2u(_Float16 h) {
  union { _Float16 h; unsigned short u; } v;
  v.h = h;
  return v.u;
}

// (256,1): the ONLY config observed to allocate 256 VGPRs spill-free (R2).
// All >=2-waves/EU hints capped the allocator at 128 and spilled (R3-R6).
// HW still co-schedules 2 blocks/CU (70.6 KB LDS) at 256 VGPR/wave.
__global__ __launch_bounds__(256, 1)
void SinglePrediction_88493506167138_kernel(
    const float* __restrict__ x,         // [B][20][2]
    const float* __restrict__ W_ih_enc,  // [256][2]
    const float* __restrict__ W_hh_enc,  // [256][64]
    const float* __restrict__ b_ih_enc,  // [256]
    const float* __restrict__ b_hh_enc,  // [256]
    const float* __restrict__ W_ih_dec,  // [256][64]
    const float* __restrict__ W_hh_dec,  // [256][64]
    const float* __restrict__ b_ih_dec,  // [256]
    const float* __restrict__ b_hh_dec,  // [256]
    const float* __restrict__ W_emb,     // [2][64]
    const float* __restrict__ b_emb,     // [2]
    float* __restrict__ out,             // [B][30][2]
    float* __restrict__ ws,              // [30][B][2] staging (if use_ws)
    int Btot, int use_ws)
{
  // LDS: 36864 (W fp16, 288 rows) + 2*16384 (hT hi/lo) + 1024 = 70,656 B
  // -> 2 blocks/CU (141 KB < 160 KB), 8 waves/CU = 2 waves/SIMD
  __shared__ __align__(16) unsigned short Wf[288 * 64];
  __shared__ __align__(16) unsigned short hTh[WAVES][32 * 64];
  __shared__ __align__(16) unsigned short hTl[WAVES][32 * 64];
  __shared__ float bsum_l[256];

  const int tid = threadIdx.x;
  const int lane = tid & 63;
  const int wid = tid >> 6;
  const int hi5 = lane >> 5;
  const int l31 = lane & 31;
  const int beb = blockIdx.x * EPB;

  // ---- stage encoder W_hh * gate-scale as fp16, XOR-swizzled:
  //      elem (row,k) -> row*64 + (k ^ ((row&7)<<3))
  for (int i = tid; i < 256 * 64; i += 256) {
    int row = i >> 6, k = i & 63;
    float sc = ((row >> 6) == 2) ? TWO_LOG2E : LOG2E;  // g-gate rows get 2L
    _Float16 wv = (_Float16)(W_hh_enc[i] * sc);
    Wf[(row << 6) | (k ^ ((row & 7) << 3))] = h2u(wv);
  }
  if (tid < 256) {
    float sc = ((tid >> 6) == 2) ? TWO_LOG2E : LOG2E;
    bsum_l[tid] = (b_ih_enc[tid] + b_hh_enc[tid]) * sc;
  }
  // ---- zero this wave's hT (h0 = 0) ----
  {
    float4 z = {0.f, 0.f, 0.f, 0.f};
    float4* p0 = (float4*)&hTh[wid][0];
    float4* p1 = (float4*)&hTl[wid][0];
    for (int i = lane; i < 256; i += 64) { p0[i] = z; p1[i] = z; }
  }
  __syncthreads();

  // per-lane constants (gate row n = nt*32 + l31), scaled like W
  float biasv[8], wi0[8], wi1[8];
#pragma unroll
  for (int nt = 0; nt < 8; nt++) {
    int n = nt * 32 + l31;
    float sc = ((n >> 6) == 2) ? TWO_LOG2E : LOG2E;
    biasv[nt] = bsum_l[n];
    float2 wv = *(const float2*)&W_ih_enc[2 * n];
    wi0[nt] = wv.x * sc;
    wi1[nt] = wv.y * sc;
  }

  float c01[2][16];
#pragma unroll
  for (int p = 0; p < 2; p++)
#pragma unroll
    for (int q = 0; q < 16; q++) c01[p][q] = 0.f;

  const int sw = (l31 & 7) << 3;  // swizzle term (same for A and B)
  const int kbase = hi5 << 3;     // k-offset of this lane half

  half8 ah[4], al[4];
  auto loadA = [&]() {
#pragma unroll
    for (int kt = 0; kt < 4; kt++) {
      int sk = (kt * 16 + kbase) ^ sw;
      ah[kt] = *(const half8*)&hTh[wid][(l31 << 6) + sk];
      al[kt] = *(const half8*)&hTl[wid][(l31 << 6) + sk];
    }
  };

  // gates MFMA: 8 N-tiles x 4 K-chunks x (h_hi + h_lo) products
  auto gemm_main = [&](f32x16 (&acc)[8]) {
#pragma unroll
    for (int kt = 0; kt < 4; kt++) {
      const int sk = (kt * 16 + kbase) ^ sw;
      half8 b[8];
#pragma unroll
      for (int nt = 0; nt < 8; nt++)
        b[nt] = *(const half8*)&Wf[((nt * 32 + l31) << 6) + sk];
#pragma unroll
      for (int nt = 0; nt < 8; nt++) acc[nt] = MFMA16(ah[kt], b[nt], acc[nt]);
#pragma unroll
      for (int nt = 0; nt < 8; nt++) acc[nt] = MFMA16(al[kt], b[nt], acc[nt]);
    }
  };

  // gates pre-scaled by log2e (2*log2e for g) -> exp2 direct
  auto finish_step = [&](f32x16 (&acc)[8]) {
#pragma unroll
    for (int p = 0; p < 2; p++)
#pragma unroll
      for (int q = 0; q < 16; q++) {
        float ig = RCPF(1.f + EXP2F(-acc[0 + p][q]));
        float fg = RCPF(1.f + EXP2F(-acc[2 + p][q]));
        float eg = EXP2F(acc[4 + p][q]);
        float gg = 1.f - 2.f * RCPF(eg + 1.f);
        float og = RCPF(1.f + EXP2F(-acc[6 + p][q]));
        float cn = fmaf(fg, c01[p][q], ig * gg);
        c01[p][q] = cn;
        float ec = EXP2F(TWO_LOG2E * cn);
        float th = 1.f - 2.f * RCPF(ec + 1.f);
        float hn = og * th;
        _Float16 hh = (_Float16)hn;
        _Float16 hl = (_Float16)(hn - (float)hh);
        const int row = (q & 3) + 8 * (q >> 2) + 4 * hi5;
        const int col = l31 + 32 * p;
        const int si = (row << 6) | (col ^ ((row & 7) << 3));
        hTh[wid][si] = h2u(hh);
        hTl[wid][si] = h2u(hl);
      }
  };

  // ================= encoder =================
#pragma unroll 1
  for (int t = 0; t < T_ENC; t++) {
    loadA();
    f32x16 acc[8];
#pragma unroll
    for (int q = 0; q < 16; q++) {
      const int row = (q & 3) + 8 * (q >> 2) + 4 * hi5;
      const float2 xq =
          *(const float2*)&x[((size_t)(beb + wid * 32 + row)) * 40 + 2 * t];
#pragma unroll
      for (int nt = 0; nt < 8; nt++)
        acc[nt][q] = fmaf(xq.x, wi0[nt], fmaf(xq.y, wi1[nt], biasv[nt]));
    }
    gemm_main(acc);
    finish_step(acc);
  }

  // ================= swap to decoder weights (+ W_emb rows 256..287) =======
  __syncthreads();
  for (int i = tid; i < 288 * 64; i += 256) {
    int row = i >> 6, k = i & 63;
    float w;
    if (row < 256) {
      float sc = ((row >> 6) == 2) ? TWO_LOG2E : LOG2E;
      w = (W_ih_dec[i] + W_hh_dec[i]) * sc;  // dec input == h: fold ih+hh
    } else if (row < 258) {
      w = W_emb[(row - 256) * 64 + k];       // unscaled
    } else {
      w = 0.f;
    }
    _Float16 wv = (_Float16)w;
    Wf[(row << 6) | (k ^ ((row & 7) << 3))] = h2u(wv);
  }
  if (tid < 256) {
    float sc = ((tid >> 6) == 2) ? TWO_LOG2E : LOG2E;
    bsum_l[tid] = (b_ih_dec[tid] + b_hh_dec[tid]) * sc;
  }
  __syncthreads();

#pragma unroll
  for (int nt = 0; nt < 8; nt++) biasv[nt] = bsum_l[nt * 32 + l31];
  const float bev = (l31 == 0) ? b_emb[0] : b_emb[1];

  // pos_{tout} from current A-frags (h after step tout+1): 9th N-tile MFMA
  auto do_pos = [&](int tout) {
    f32x16 accP;
#pragma unroll
    for (int q = 0; q < 16; q++) accP[q] = 0.f;
#pragma unroll
    for (int kt = 0; kt < 4; kt++) {
      int sk = (kt * 16 + kbase) ^ sw;
      int r = 256 + l31;
      half8 be = *(const half8*)&Wf[(r << 6) + sk];
      accP = MFMA16(ah[kt], be, accP);
      accP = MFMA16(al[kt], be, accP);
    }
    if (l31 < 2) {
#pragma unroll
      for (int q = 0; q < 16; q++) {
        int row = (q & 3) + 8 * (q >> 2) + 4 * hi5;
        size_t e = (size_t)(beb + wid * 32 + row);
        float v = accP[q] + bev;
        if (use_ws) {
          // [T][B][2]: per wave-step the stores cover one contiguous 256 B
          // region -> full-line write-combine, no RMW fetch
          ws[((size_t)tout * Btot + e) * 2 + l31] = v;
        } else {
          out[e * 60 + 2 * tout + l31] = v;
        }
      }
    }
  };

  // ================= decoder =================
#pragma unroll 1
  for (int t = 0; t < T_DEC; t++) {
    loadA();
    if (t > 0) do_pos(t - 1);
    f32x16 acc[8];
#pragma unroll
    for (int nt = 0; nt < 8; nt++)
#pragma unroll
      for (int q = 0; q < 16; q++) acc[nt][q] = biasv[nt];
    gemm_main(acc);
    finish_step(acc);
  }
  loadA();
  do_pos(T_DEC - 1);
}

// ws [30][B][2] -> out [B][30][2]; reads coalesced, per-thread writes cover
// a contiguous 240 B span (wave covers 15 KB fully -> write-combine in L2)
__global__ __launch_bounds__(256)
void pos_transpose_kernel(const float* __restrict__ ws,
                          float* __restrict__ out, int Btot) {
  const int e = blockIdx.x * 256 + threadIdx.x;
  float2 v[T_DEC];
#pragma unroll
  for (int t = 0; t < T_DEC; t++)
    v[t] = ((const float2*)ws)[(size_t)t * Btot + e];
  float2* o = (float2*)(out + (size_t)e * 60);
#pragma unroll
  for (int t = 0; t < T_DEC; t++) o[t] = v[t];
}

extern "C" void kernel_launch(void* const* d_in, const int* in_sizes, int n_in,
                              void* d_out, int out_size, void* d_ws, size_t ws_size,
                              hipStream_t stream) {
  const float* x        = (const float*)d_in[0];
  const float* W_ih_enc = (const float*)d_in[1];
  const float* W_hh_enc = (const float*)d_in[2];
  const float* b_ih_enc = (const float*)d_in[3];
  const float* b_hh_enc = (const float*)d_in[4];
  const float* W_ih_dec = (const float*)d_in[5];
  const float* W_hh_dec = (const float*)d_in[6];
  const float* b_ih_dec = (const float*)d_in[7];
  const float* b_hh_dec = (const float*)d_in[8];
  const float* W_emb    = (const float*)d_in[9];
  const float* b_emb    = (const float*)d_in[10];
  float* out = (float*)d_out;

  const int B = in_sizes[0] / (T_ENC * 2);  // 65536
  const int grid = B / EPB;                 // 512 = 2 resident blocks per CU
  const size_t ws_needed = (size_t)B * T_DEC * 2 * sizeof(float);
  const int use_ws = (ws_size >= ws_needed) ? 1 : 0;

  hipLaunchKernelGGL(SinglePrediction_88493506167138_kernel,
                     dim3(grid), dim3(256), 0, stream,
                     x, W_ih_enc, W_hh_enc, b_ih_enc, b_hh_enc,
                     W_ih_dec, W_hh_dec, b_ih_dec, b_hh_dec,
                     W_emb, b_emb, out, (float*)d_ws, B, use_ws);
  if (use_ws) {
    hipLaunchKernelGGL(pos_transpose_kernel, dim3(B / 256), dim3(256), 0,
                       stream, (const float*)d_ws, out, B);
  }
}